// Round 4
// baseline (1153.095 us; speedup 1.0000x reference)
//
#include <hip/hip_runtime.h>

#define MAX_ITER 8192
#define NCHUNK   64
#define NCHUNKS  128          // MAX_ITER / NCHUNK
#define NSCAN    64           // scanner blocks, 1 sample each
#define NTHREADS 256

typedef unsigned long long u64;
#define KEY_MAX  0xffffffffffffffffull
#define POISON64 0xAAAAAAAAAAAAAAAAull   // d_ws re-poison pattern (0xAA bytes)

// IEEE fp32 ops, contraction off -> bitwise numpy match (verified rounds 2-7).
__device__ __forceinline__ float mul_rn(float a, float b) {
#pragma clang fp contract(off)
  return a * b;
}
__device__ __forceinline__ float add_rn(float a, float b) {
#pragma clang fp contract(off)
  return a + b;
}
__device__ __forceinline__ float sub_rn(float a, float b) {
#pragma clang fp contract(off)
  return a - b;
}
__device__ __forceinline__ float bcastf(float v, int lane) {
  return __int_as_float(__builtin_amdgcn_readlane(__float_as_int(v), lane));
}
__device__ __forceinline__ void st_agent(u64* p, u64 v) {
  __hip_atomic_store(p, v, __ATOMIC_RELAXED, __HIP_MEMORY_SCOPE_AGENT);
}
__device__ __forceinline__ u64 ld_agent(u64* p) {
  return __hip_atomic_load(p, __ATOMIC_RELAXED, __HIP_MEMORY_SCOPE_AGENT);
}
__device__ __forceinline__ u64 packf2(float x, float y) {
  return ((u64)__float_as_uint(y) << 32) | (u64)__float_as_uint(x);
}
__device__ __forceinline__ void compiler_fence() {
  asm volatile("" ::: "memory");
}
// Exact (d2, idx) lexicographic key: d2 >= 0 -> bit-monotonic; ties -> low idx.
// idx in bits 0..12; tag in bits 13..20 (values 131..255; 0xAA poison tag=85).
__device__ __forceinline__ u64 mkkey(float d2, int idx) {
  return ((u64)__float_as_uint(d2) << 32) | (u64)(unsigned)idx;
}

__global__ __launch_bounds__(NTHREADS) void rrt_kernel(
    const float* __restrict__ state, const float* __restrict__ goal,
    const float* __restrict__ u, const float* __restrict__ r,
    float* __restrict__ out, unsigned* __restrict__ ws) {
  // coordinator (block 0): own LDS node copy -> M-index resolves via ds_read.
  // scanners: nodes staged from the poison-gated Nb broadcast buffer.
  __shared__ __align__(16) float2 nodesL[8064];
  __shared__ u64 sharedK[4];

  u64* outU  = (u64*)out;               // node i at outU[i] (float2-packed)
  // MbufK: 4-slot ring of 64 tagged keys.  Scanner iter i writes slot i&3
  // with tag i+131 (M for coordinator chunk j=i+3, computed vs chunk j's
  // sample).  Coordinator chunk j reads slot (j-3)&3 requiring tag == j+128
  // EXACTLY (tags are sample-specific -- r3's ">=" accepted Ms computed
  // against wrong samples).  Ring safety: slot reuse (iter i+4) needs Nb
  // chunk i+4, published only after the coordinator's chunk-(i+3) merge
  // consumed iter i's M (merge -> nodes -> Nb data dependence).
  u64* MbufK = (u64*)(ws + 64);         // bytes 256..2303 (4*64*8)
  u64* Nb    = (u64*)(ws + 576);        // bytes 2304..66815
  // Nb[m] = node m+1, written ONCE; 0xAA poison = impossible node value
  // (nodes are >= 0; 0xAAAAAAAA is a tiny NEGATIVE float).  Self-validating:
  // the data IS the ready flag -> no nflag, no store drain, no init guard.

  const int tid  = threadIdx.x;
  const int wave = tid >> 6;
  const int lane = tid & 63;
  const int blk  = blockIdx.x;

  const float n0x = state[0], n0y = state[1];
  const float gx = goal[0],  gy = goal[1];

  if (blk == 0) {
    // ================= coordinator: one wave =====================
    if (tid == 0) st_agent(&outU[0], packf2(n0x, n0y));   // node 0 (output only)
    if (tid >= 64) return;

    float sx, sy, s1x, s1y;               // samples: current, next
    {
      const float uu = u[lane];
      if (uu < 0.1f) { sx = gx; sy = gy; }
      else { sx = mul_rn(r[2 * lane], 200.0f); sy = mul_rn(r[2 * lane + 1], 200.0f); }
      const int i1 = NCHUNK + lane;
      const float u1 = u[i1];
      if (u1 < 0.1f) { s1x = gx; s1y = gy; }
      else { s1x = mul_rn(r[2 * i1], 200.0f); s1y = mul_rn(r[2 * i1 + 1], 200.0f); }
    }
    // 2-deep carries: c1 merged this chunk, c2 becomes c1 next chunk.
    // At chunk j's merge, c1 covers nodes of chunks j-2, j-1 vs chunk j's
    // sample (folded during those chunks' inner loops against s1/s2).
    float c1d = 3.0e38f, c1x = 0.0f, c1y = 0.0f;
    float c2d = 3.0e38f, c2x = 0.0f, c2y = 0.0f;
    u64 kvPre = 0;

    for (int j = 0; j < NCHUNKS; ++j) {
      const int c = j * NCHUNK;

      // prefetch sample for chunk j+2 (independent L2 loads)
      float s2x = 0.0f, s2y = 0.0f;
      if (j + 2 < NCHUNKS) {
        const int i2 = c + 2 * NCHUNK + lane;
        const float uu = u[i2];
        if (uu < 0.1f) { s2x = gx; s2y = gy; }
        else { s2x = mul_rn(r[2 * i2], 200.0f); s2y = mul_rn(r[2 * i2 + 1], 200.0f); }
      }

      // ---- assemble argmin over [0..64j]:
      //   j<3 : node 0 + carry (disjoint, node0 wins ties: lower idx)
      //   j>=3: scanner M (tag == j+128, covers [0..64(j-2)]) + carry
      //         (covers (64(j-2)..64j]).  Disjoint; M wins ties (lower idx).
      float bd2, bx, by;
      if (j == 0) {
        const float dx = sub_rn(n0x, sx), dy = sub_rn(n0y, sy);
        bd2 = add_rn(mul_rn(dx, dx), mul_rn(dy, dy));
        bx = n0x; by = n0y;
      } else if (j < 3) {
        const float dx = sub_rn(n0x, sx), dy = sub_rn(n0y, sy);
        bd2 = add_rn(mul_rn(dx, dx), mul_rn(dy, dy));
        bx = n0x; by = n0y;
        if (c1d < bd2) { bd2 = c1d; bx = c1x; by = c1y; }
      } else {
        u64* slot = MbufK + (((unsigned)(j - 3)) & 3u) * 64;
        u64 kv = kvPre;   // issued one full chunk ago -> normally a hit
        if (!__all((int)((((unsigned)(kv >> 13)) & 0xFFu) == (unsigned)(j + 128)))) {
          for (;;) {
            kv = ld_agent(&slot[lane]);
            if (__all((int)((((unsigned)(kv >> 13)) & 0xFFu) == (unsigned)(j + 128)))) break;
            __builtin_amdgcn_s_sleep(1);
          }
        }
        compiler_fence();
        const float md2 = __uint_as_float((unsigned)(kv >> 32));
        const unsigned midx = (unsigned)kv & 0x1FFFu;
        bd2 = c1d; bx = c1x; by = c1y;
        if (!(bd2 < md2)) {   // M wins ties (disjoint lower-index range)
          bd2 = md2;
          if (midx == 0u) { bx = n0x; by = n0y; }
          else { const float2 p = nodesL[midx - 1]; bx = p.x; by = p.y; }
        }
      }

      // carry shift (AFTER merge): c1 <- c2, c2 <- fresh
      c1d = c2d; c1x = c2x; c1y = c2y;
      c2d = 3.0e38f; c2x = 0.0f; c2y = 0.0f;

      // speculative ring load for NEXT chunk's merge (slot (j-2)&3); in
      // flight across the whole inner loop.  Wrong/stale -> poll fallback.
      if (j >= 2 && j < NCHUNKS - 1) {
        u64* nslot = MbufK + (((unsigned)(j - 2)) & 3u) * 64;
        kvPre = ld_agent(&nslot[lane]);
      }

      // pre-steer (round-3-verified math)
      float nx, ny;
      {
        const float dirx = sub_rn(sx, bx), diry = sub_rn(sy, by);
        const float dist = __fsqrt_rn(add_rn(bd2, 1e-12f));
        const float scl = (dist > 5.0f) ? __fdiv_rn(5.0f, dist) : 1.0f;
        nx = add_rn(bx, mul_rn(dirx, scl));
        ny = add_rn(by, mul_rn(diry, scl));
      }

      // ---- 64 steps in groups of 8: speculative batched broadcasts.
      // Stale broadcasts require an update by a lane INSIDE the group window;
      // the first such update (sequential order) is computed from valid data
      // and satisfies min(da) < bd2_entry -> conservatively detected.
      #pragma unroll
      for (int g = 0; g < NCHUNK; g += 8) {
        float qx[8], qy[8], da[8];
        #pragma unroll
        for (int jj = 0; jj < 8; ++jj) {
          qx[jj] = bcastf(nx, g + jj);   // node c+g+jj+1 (speculative)
          qy[jj] = bcastf(ny, g + jj);
        }
        #pragma unroll
        for (int jj = 0; jj < 8; ++jj) {
          const float dx = sub_rn(qx[jj], sx), dy = sub_rn(qy[jj], sy);
          da[jj] = add_rn(mul_rn(dx, dx), mul_rn(dy, dy));
        }
        const float m8 = fminf(fminf(fminf(da[0], da[1]), fminf(da[2], da[3])),
                               fminf(fminf(da[4], da[5]), fminf(da[6], da[7])));
        const bool cond = (m8 < bd2);

        if (__builtin_expect(__any((int)(cond && lane > g && lane < g + 8)), 0)) {
          // ---- danger: exact sequential replay of steps g..g+7 (rare) ----
          #pragma unroll
          for (int jj = 0; jj < 8; ++jj) {
            const int t = g + jj;
            const float px = bcastf(nx, t);
            const float py = bcastf(ny, t);
            if (lane > t) {
              const float dx = sub_rn(px, sx), dy = sub_rn(py, sy);
              const float nd2 = add_rn(mul_rn(dx, dx), mul_rn(dy, dy));
              if (nd2 < bd2) {
                bd2 = nd2; bx = px; by = py;
                const float dirx = sub_rn(sx, bx), diry = sub_rn(sy, by);
                const float dist = __fsqrt_rn(add_rn(nd2, 1e-12f));
                const float scl = (dist > 5.0f) ? __fdiv_rn(5.0f, dist) : 1.0f;
                nx = add_rn(bx, mul_rn(dirx, scl));
                ny = add_rn(by, mul_rn(diry, scl));
              }
            }
            {   // 2-deep carried folds (ascending index, strict <)
              const float dx1 = sub_rn(px, s1x), dy1 = sub_rn(py, s1y);
              const float d1 = add_rn(mul_rn(dx1, dx1), mul_rn(dy1, dy1));
              if (d1 < c1d) { c1d = d1; c1x = px; c1y = py; }
              const float dx2 = sub_rn(px, s2x), dy2 = sub_rn(py, s2y);
              const float d2_ = add_rn(mul_rn(dx2, dx2), mul_rn(dy2, dy2));
              if (d2_ < c2d) { c2d = d2_; c2x = px; c2y = py; }
            }
          }
        } else {
          // ---- fast path: broadcasts valid; lanes >= g+8 fold updates ----
          const bool apply = cond && (lane >= g + 8);
          if (__builtin_expect(__any((int)apply), 0)) {
            if (apply) {
              #pragma unroll
              for (int jj = 0; jj < 8; ++jj) {   // ascending strict <: exact
                if (da[jj] < bd2) { bd2 = da[jj]; bx = qx[jj]; by = qy[jj]; }
              }
              const float dirx = sub_rn(sx, bx), diry = sub_rn(sy, by);
              const float dist = __fsqrt_rn(add_rn(bd2, 1e-12f));
              const float scl = (dist > 5.0f) ? __fdiv_rn(5.0f, dist) : 1.0f;
              nx = add_rn(bx, mul_rn(dirx, scl));
              ny = add_rn(by, mul_rn(diry, scl));
            }
          }
          #pragma unroll
          for (int jj = 0; jj < 8; ++jj) {   // 2-deep carried folds
            const float dx1 = sub_rn(qx[jj], s1x), dy1 = sub_rn(qy[jj], s1y);
            const float d1 = add_rn(mul_rn(dx1, dx1), mul_rn(dy1, dy1));
            if (d1 < c1d) { c1d = d1; c1x = qx[jj]; c1y = qy[jj]; }
            const float dx2 = sub_rn(qx[jj], s2x), dy2 = sub_rn(qy[jj], s2y);
            const float d2_ = add_rn(mul_rn(dx2, dx2), mul_rn(dy2, dy2));
            if (d2_ < c2d) { c2d = d2_; c2x = qx[jj]; c2y = qy[jj]; }
          }
        }
      }

      // publish: LDS self-copy + output + poison-gated broadcast.  No drain,
      // no flag: Nb values are self-validating.
      if (c + lane < 8064) {
        float2 p; p.x = nx; p.y = ny;
        nodesL[c + lane] = p;             // node c+lane+1 at LDS idx c+lane
      }
      const u64 pv = packf2(nx, ny);
      st_agent(&outU[c + lane + 1], pv);
      st_agent(&Nb[c + lane], pv);

      sx = s1x; sy = s1y; s1x = s2x; s1y = s2y;
    }
  } else {
    // ================= scanners: blocks 1..64, one sample each =============
    // iter i (0..124): issue Nb load for chunk i; bulk-scan [0..64i] from LDS
    // (staged in prior iters) under it; wave-0 tail validates the 64 fresh
    // chunk-i nodes, folds one each, publishes tag i+131 into ring slot i&3.
    // M is computed vs chunk (i+3)'s sample -> consumed at coordinator chunk
    // j=i+3 with tag equality.  Published ~2 chunk periods before use.
    const int b = blk - 1;

    for (int i = 0; i < NCHUNKS - 3; ++i) {
      const int c = i * NCHUNK;

      u64 nv = POISON64;
      if (wave == 0) nv = ld_agent(&Nb[c + lane]);   // issue early, check late

      // my sample: chunk i+3, slot b
      float sx, sy;
      {
        const int ii = (i + 3) * NCHUNK + b;
        const float uu = u[ii];
        if (uu < 0.1f) { sx = gx; sy = gy; }
        else { sx = mul_rn(r[2 * ii], 200.0f); sy = mul_rn(r[2 * ii + 1], 200.0f); }
      }

      // ---- bulk scan of staged nodes [1..64i] + node 0 ----
      u64 key = KEY_MAX;
      if (tid == 0) {
        const float dx = sub_rn(n0x, sx), dy = sub_rn(n0y, sy);
        key = mkkey(add_rn(mul_rn(dx, dx), mul_rn(dy, dy)), 0);
      }
      for (int jj = 1 + 2 * tid; jj < c; jj += 2 * NTHREADS) {
        const float4 p = *(const float4*)&nodesL[jj - 1];
        const float dxa = sub_rn(p.x, sx), dya = sub_rn(p.y, sy);
        const u64 ka = mkkey(add_rn(mul_rn(dxa, dxa), mul_rn(dya, dya)), jj);
        const float dxb = sub_rn(p.z, sx), dyb = sub_rn(p.w, sy);
        const u64 kb = mkkey(add_rn(mul_rn(dxb, dxb), mul_rn(dyb, dyb)), jj + 1);
        if (ka < key) key = ka;
        if (kb < key) key = kb;
      }
      #pragma unroll
      for (int m = 32; m >= 1; m >>= 1) {
        const u64 ok = __shfl_xor(key, m, 64);
        if (ok < key) key = ok;
      }
      if (lane == 0) sharedK[wave] = key;
      __syncthreads();

      // ---- wave-0 tail: validate fresh chunk i, fold, publish, stage ----
      if (wave == 0) {
        u64 kk = (lane < 4) ? sharedK[lane] : KEY_MAX;
        u64 ok = __shfl_xor(kk, 1, 64); if (ok < kk) kk = ok;
        ok = __shfl_xor(kk, 2, 64);     if (ok < kk) kk = ok;

        while (!__all((int)(nv != POISON64))) {   // normally already valid
          __builtin_amdgcn_s_sleep(1);
          nv = ld_agent(&Nb[c + lane]);
        }
        compiler_fence();
        const float px = __uint_as_float((unsigned)(nv & 0xffffffffu));
        const float py = __uint_as_float((unsigned)(nv >> 32));
        {
          const float dx = sub_rn(px, sx), dy = sub_rn(py, sy);
          const u64 ki = mkkey(add_rn(mul_rn(dx, dx), mul_rn(dy, dy)), c + lane + 1);
          if (ki < kk) kk = ki;
        }
        #pragma unroll
        for (int m = 32; m >= 1; m >>= 1) {
          const u64 o2 = __shfl_xor(kk, m, 64);
          if (o2 < kk) kk = o2;
        }
        if (lane == 0) {
          u64* slot = MbufK + (((unsigned)i) & 3u) * 64;
          st_agent(&slot[b], kk | ((u64)(unsigned)(i + 131) << 13));
        }
        float2 p; p.x = px; p.y = py;
        nodesL[c + lane] = p;             // stage chunk i for next bulk
      }
      // gate: next bulk reads chunk i; sharedK reused next iter.
      __syncthreads();
    }
  }
}

extern "C" void kernel_launch(void* const* d_in, const int* in_sizes, int n_in,
                              void* d_out, int out_size, void* d_ws, size_t ws_size,
                              hipStream_t stream) {
  const float* state = (const float*)d_in[0];
  const float* goal  = (const float*)d_in[1];
  const float* u     = (const float*)d_in[2];
  const float* r     = (const float*)d_in[3];
  float* out = (float*)d_out;
  unsigned* ws = (unsigned*)d_ws;
  (void)in_sizes; (void)n_in; (void)out_size; (void)ws_size;
  rrt_kernel<<<NSCAN + 1, NTHREADS, 0, stream>>>(state, goal, u, r, out, ws);
}

// Round 5
// 1128.702 us; speedup vs baseline: 1.0216x; 1.0216x over previous
//
#include <hip/hip_runtime.h>

#define MAX_ITER 8192
#define NCHUNK   64
#define NCHUNKS  128          // MAX_ITER / NCHUNK
#define NSCAN    64           // scanner blocks, 1 sample each
#define NTHREADS 256

typedef unsigned long long u64;
#define KEY_MAX  0xffffffffffffffffull
#define POISON64 0xAAAAAAAAAAAAAAAAull   // d_ws re-poison pattern (0xAA bytes)

// IEEE fp32 ops, contraction off -> bitwise numpy match (verified rounds 2-7).
__device__ __forceinline__ float mul_rn(float a, float b) {
#pragma clang fp contract(off)
  return a * b;
}
__device__ __forceinline__ float add_rn(float a, float b) {
#pragma clang fp contract(off)
  return a + b;
}
__device__ __forceinline__ float sub_rn(float a, float b) {
#pragma clang fp contract(off)
  return a - b;
}
__device__ __forceinline__ float bcastf(float v, int lane) {
  return __int_as_float(__builtin_amdgcn_readlane(__float_as_int(v), lane));
}
__device__ __forceinline__ void st_agent(u64* p, u64 v) {
  __hip_atomic_store(p, v, __ATOMIC_RELAXED, __HIP_MEMORY_SCOPE_AGENT);
}
__device__ __forceinline__ u64 ld_agent(u64* p) {
  return __hip_atomic_load(p, __ATOMIC_RELAXED, __HIP_MEMORY_SCOPE_AGENT);
}
__device__ __forceinline__ u64 packf2(float x, float y) {
  return ((u64)__float_as_uint(y) << 32) | (u64)__float_as_uint(x);
}
__device__ __forceinline__ float lo32f(u64 v) {
  return __uint_as_float((unsigned)(v & 0xffffffffu));
}
__device__ __forceinline__ float hi32f(u64 v) {
  return __uint_as_float((unsigned)(v >> 32));
}
__device__ __forceinline__ void compiler_fence() {
  asm volatile("" ::: "memory");
}
// Exact (d2, idx) lexicographic key: d2 >= 0 -> bit-monotonic; ties -> low idx.
// Scanner keys: idx bits 0..12, tag bits 13..20 (132..255; 0xAA poison tag=85).
__device__ __forceinline__ u64 mkkey(float d2, int idx) {
  return ((u64)__float_as_uint(d2) << 32) | (u64)(unsigned)idx;
}

__global__ __launch_bounds__(NTHREADS) void rrt_kernel(
    const float* __restrict__ state, const float* __restrict__ goal,
    const float* __restrict__ u, const float* __restrict__ r,
    float* __restrict__ out, unsigned* __restrict__ ws) {
  // LDS union: scanner blocks use .s (staged nodes + reduce slots); block 0
  // uses .h (helper-wave result ring).  Different blocks -> no aliasing.
  __shared__ __align__(16) union {
    struct { float2 nodes[7936]; u64 K[4]; } s;            // 63520 B
    struct { u64 key[2][4][64]; unsigned tag[2][4]; } h;   //  4128 B
  } sh;

  u64* outU  = (u64*)out;               // node i at outU[i] (float2-packed)
  // MbufK: 4-slot ring of 64 tagged keys.  Scanner iter i writes slot i&3,
  // tag i+132: M over [0..64(i+1)] computed vs chunk (i+4)'s sample.
  // Coordinator merge j (>=4) reads slot (j-4)&3 requiring tag == j+128
  // EXACTLY.  Slot reuse (iter i+4) needs Nb chunk i+4, which the
  // coordinator publishes only after merge j=i+4 consumed iter i's M.
  u64* MbufK = (u64*)(ws + 64);         // bytes 256..2303
  u64* Nb    = (u64*)(ws + 576);        // bytes 2304..67839
  // Nb[m] = node m+1, written ONCE; 0xAA poison = impossible node value
  // (nodes are >= 0; 0xAAAAAAAA is a tiny negative float).  Data IS the
  // ready flag -> no drain, no init guard.

  const int tid  = threadIdx.x;
  const int wave = tid >> 6;
  const int lane = tid & 63;
  const int blk  = blockIdx.x;

  const float n0x = state[0], n0y = state[1];
  const float gx = goal[0],  gy = goal[1];

  if (blk == 0) {
    // ---- one-time block-0 init: zero helper tags, then split waves ----
    if (tid < 8) sh.h.tag[tid >> 2][tid & 3] = 0u;
    __syncthreads();                    // only barrier in block 0

    if (wave == 3) return;

    if (wave >= 1) {
      // ============ helper waves: lag-2 (wave1) / lag-3 (wave2) folds ======
      // iter t: fold chunk t's 64 nodes vs sample vector of chunk t+off,
      // result (d2, node_idx) per lane -> LDS ring slot t&3, tag t+1.
      // Consumed at coordinator merge j = t+off.  Slot reuse gap = 4 chunks;
      // reuse (iter t+4) requires Nb chunk t+4 which postdates consumption.
      const int off = wave + 1;         // 2 or 3
      const int hw  = wave - 1;         // 0 or 1
      for (int t = 0; t < NCHUNKS - off; ++t) {
        // my sample: chunk t+off, slot lane
        float ssx, ssy;
        {
          const int si = (t + off) * NCHUNK + lane;
          const float uu = u[si];
          if (uu < 0.1f) { ssx = gx; ssy = gy; }
          else { ssx = mul_rn(r[2 * si], 200.0f); ssy = mul_rn(r[2 * si + 1], 200.0f); }
        }
        // chunk t's nodes via poison-gated Nb (same-XCD L2: fast)
        u64 nv = ld_agent(&Nb[t * NCHUNK + lane]);
        while (!__all((int)(nv != POISON64))) {
          __builtin_amdgcn_s_sleep(1);
          nv = ld_agent(&Nb[t * NCHUNK + lane]);
        }
        compiler_fence();
        const float px = lo32f(nv), py = hi32f(nv);
        float bd = 3.0e38f; int bi = 0;
        #pragma unroll 8
        for (int tt = 0; tt < NCHUNK; ++tt) {  // ascending, strict < -> low idx ties
          const float qx = bcastf(px, tt), qy = bcastf(py, tt);
          const float dx = sub_rn(qx, ssx), dy = sub_rn(qy, ssy);
          const float d = add_rn(mul_rn(dx, dx), mul_rn(dy, dy));
          if (d < bd) { bd = d; bi = tt; }
        }
        sh.h.key[hw][t & 3][lane] = mkkey(bd, t * NCHUNK + bi + 1);
        asm volatile("s_waitcnt lgkmcnt(0)" ::: "memory");   // keys land first
        if (lane == 0)
          __hip_atomic_store(&sh.h.tag[hw][t & 3], (unsigned)(t + 1),
                             __ATOMIC_RELAXED, __HIP_MEMORY_SCOPE_WORKGROUP);
      }
      return;
    }

    // ================= coordinator: wave 0 =====================
    if (lane == 0) st_agent(&outU[0], packf2(n0x, n0y));   // node 0

    float sx, sy, s1x, s1y;             // samples: chunk j, chunk j+1
    {
      const float uu = u[lane];
      if (uu < 0.1f) { sx = gx; sy = gy; }
      else { sx = mul_rn(r[2 * lane], 200.0f); sy = mul_rn(r[2 * lane + 1], 200.0f); }
      const int i1 = NCHUNK + lane;
      const float u1 = u[i1];
      if (u1 < 0.1f) { s1x = gx; s1y = gy; }
      else { s1x = mul_rn(r[2 * i1], 200.0f); s1y = mul_rn(r[2 * i1 + 1], 200.0f); }
    }
    // lag-1 carry: folded during chunk j-1's inner loop vs s_j
    float c1d = 3.0e38f, c1x = 0.0f, c1y = 0.0f;
    // speculative MbufK loads: kvLate issued 1 chunk before use, kvEarly 2.
    u64 kvLate = 0, kvEarly = 0, kvEarlyNext = 0;

    for (int j = 0; j < NCHUNKS; ++j) {
      const int c = j * NCHUNK;

      // prefetch sample for chunk j+2 (independent; used as s1 next chunk)
      float s2x = 0.0f, s2y = 0.0f;
      if (j + 2 < NCHUNKS) {
        const int i2 = c + 2 * NCHUNK + lane;
        const float uu = u[i2];
        if (uu < 0.1f) { s2x = gx; s2y = gy; }
        else { s2x = mul_rn(r[2 * i2], 200.0f); s2y = mul_rn(r[2 * i2 + 1], 200.0f); }
      }

      // ---- merge argmin over [0..64j], candidates in ascending range order:
      //   M (scanner): node0 + chunks <= j-4   [j>=4; else explicit node0]
      //   h2 (wave2):  chunk j-3               [j>=3]
      //   h1 (wave1):  chunk j-2               [j>=2]
      //   c1 (own):    chunk j-1               [j>=1]
      // Disjoint ranges; strict < keeps earlier candidate on ties -> exact.
      float bd2; unsigned bidx;          // bidx==0 -> node 0
      if (j >= 4) {
        const unsigned want = (unsigned)(j + 128);
        u64 kv = kvLate;
        if (!__all((int)((((unsigned)(kv >> 13)) & 0xFFu) == want))) {
          kv = kvEarly;
          if (!__all((int)((((unsigned)(kv >> 13)) & 0xFFu) == want))) {
            u64* slot = MbufK + (((unsigned)(j - 4)) & 3u) * 64;
            for (;;) {
              kv = ld_agent(&slot[lane]);
              if (__all((int)((((unsigned)(kv >> 13)) & 0xFFu) == want))) break;
              __builtin_amdgcn_s_sleep(1);
            }
          }
        }
        compiler_fence();
        bd2 = hi32f(kv); bidx = (unsigned)kv & 0x1FFFu;
      } else {
        const float dx = sub_rn(n0x, sx), dy = sub_rn(n0y, sy);
        bd2 = add_rn(mul_rn(dx, dx), mul_rn(dy, dy));
        bidx = 0u;
      }
      if (j >= 3) {   // h2: chunk j-3 vs s_j, tag j-2
        const int sl = (j - 3) & 3;
        while (__hip_atomic_load(&sh.h.tag[1][sl], __ATOMIC_RELAXED,
                                 __HIP_MEMORY_SCOPE_WORKGROUP) != (unsigned)(j - 2))
          __builtin_amdgcn_s_sleep(1);
        compiler_fence();
        const u64 hk = sh.h.key[1][sl][lane];
        const float hd = hi32f(hk);
        if (hd < bd2) { bd2 = hd; bidx = (unsigned)hk & 0x1FFFu; }
      }
      if (j >= 2) {   // h1: chunk j-2 vs s_j, tag j-1
        const int sl = (j - 2) & 3;
        while (__hip_atomic_load(&sh.h.tag[0][sl], __ATOMIC_RELAXED,
                                 __HIP_MEMORY_SCOPE_WORKGROUP) != (unsigned)(j - 1))
          __builtin_amdgcn_s_sleep(1);
        compiler_fence();
        const u64 hk = sh.h.key[0][sl][lane];
        const float hd = hi32f(hk);
        if (hd < bd2) { bd2 = hd; bidx = (unsigned)hk & 0x1FFFu; }
      }
      // winner coords: gather issued before the c1 compare to hide latency
      const unsigned gidx = (bidx == 0u) ? 1u : bidx;
      const u64 wv = ld_agent(&Nb[gidx - 1]);   // own-XCD L2 hit
      bool useC1 = false;
      if (c1d < bd2) { bd2 = c1d; useC1 = true; }
      float bx, by;
      if (useC1)            { bx = c1x;      by = c1y; }
      else if (bidx == 0u)  { bx = n0x;      by = n0y; }
      else                  { bx = lo32f(wv); by = hi32f(wv); }

      // reset carry for this chunk's folding (consumed above)
      c1d = 3.0e38f; c1x = 0.0f; c1y = 0.0f;

      // pre-steer (round-3-verified math)
      float nx, ny;
      {
        const float dirx = sub_rn(sx, bx), diry = sub_rn(sy, by);
        const float dist = __fsqrt_rn(add_rn(bd2, 1e-12f));
        const float scl = (dist > 5.0f) ? __fdiv_rn(5.0f, dist) : 1.0f;
        nx = add_rn(bx, mul_rn(dirx, scl));
        ny = add_rn(by, mul_rn(diry, scl));
      }

      // ---- 64 steps in groups of 8: speculative batched broadcasts.
      // Stale broadcasts require an update by a lane INSIDE the group window;
      // the first such update (sequential order) is computed from valid data
      // and satisfies min(da) < bd2_entry -> conservatively detected.
      #pragma unroll
      for (int g = 0; g < NCHUNK; g += 8) {
        float qx[8], qy[8], da[8];
        #pragma unroll
        for (int jj = 0; jj < 8; ++jj) {
          qx[jj] = bcastf(nx, g + jj);   // node c+g+jj+1 (speculative)
          qy[jj] = bcastf(ny, g + jj);
        }
        #pragma unroll
        for (int jj = 0; jj < 8; ++jj) {
          const float dx = sub_rn(qx[jj], sx), dy = sub_rn(qy[jj], sy);
          da[jj] = add_rn(mul_rn(dx, dx), mul_rn(dy, dy));
        }
        const float m8 = fminf(fminf(fminf(da[0], da[1]), fminf(da[2], da[3])),
                               fminf(fminf(da[4], da[5]), fminf(da[6], da[7])));
        const bool cond = (m8 < bd2);

        if (__builtin_expect(__any((int)(cond && lane > g && lane < g + 8)), 0)) {
          // ---- danger: exact sequential replay of steps g..g+7 (rare) ----
          #pragma unroll
          for (int jj = 0; jj < 8; ++jj) {
            const int t = g + jj;
            const float px = bcastf(nx, t);
            const float py = bcastf(ny, t);
            if (lane > t) {
              const float dx = sub_rn(px, sx), dy = sub_rn(py, sy);
              const float nd2 = add_rn(mul_rn(dx, dx), mul_rn(dy, dy));
              if (nd2 < bd2) {
                bd2 = nd2; bx = px; by = py;
                const float dirx = sub_rn(sx, bx), diry = sub_rn(sy, by);
                const float dist = __fsqrt_rn(add_rn(nd2, 1e-12f));
                const float scl = (dist > 5.0f) ? __fdiv_rn(5.0f, dist) : 1.0f;
                nx = add_rn(bx, mul_rn(dirx, scl));
                ny = add_rn(by, mul_rn(diry, scl));
              }
            }
            {   // lag-1 carried fold (ascending index, strict <)
              const float dx1 = sub_rn(px, s1x), dy1 = sub_rn(py, s1y);
              const float d1 = add_rn(mul_rn(dx1, dx1), mul_rn(dy1, dy1));
              if (d1 < c1d) { c1d = d1; c1x = px; c1y = py; }
            }
          }
        } else {
          // ---- fast path: broadcasts valid; lanes >= g+8 fold updates ----
          const bool apply = cond && (lane >= g + 8);
          if (__builtin_expect(__any((int)apply), 0)) {
            if (apply) {
              #pragma unroll
              for (int jj = 0; jj < 8; ++jj) {   // ascending strict <: exact
                if (da[jj] < bd2) { bd2 = da[jj]; bx = qx[jj]; by = qy[jj]; }
              }
              const float dirx = sub_rn(sx, bx), diry = sub_rn(sy, by);
              const float dist = __fsqrt_rn(add_rn(bd2, 1e-12f));
              const float scl = (dist > 5.0f) ? __fdiv_rn(5.0f, dist) : 1.0f;
              nx = add_rn(bx, mul_rn(dirx, scl));
              ny = add_rn(by, mul_rn(diry, scl));
            }
          }
          #pragma unroll
          for (int jj = 0; jj < 8; ++jj) {   // lag-1 carried fold
            const float dx1 = sub_rn(qx[jj], s1x), dy1 = sub_rn(qy[jj], s1y);
            const float d1 = add_rn(mul_rn(dx1, dx1), mul_rn(dy1, dy1));
            if (d1 < c1d) { c1d = d1; c1x = qx[jj]; c1y = qy[jj]; }
          }
        }
      }

      // publish (self-validating; no drain): output + broadcast
      const u64 pv = packf2(nx, ny);
      st_agent(&outU[c + lane + 1], pv);
      st_agent(&Nb[c + lane], pv);

      // speculative MbufK issues: kvLate for merge j+1 (slot (j-3)&3),
      // kvEarlyNext for merge j+2 (slot (j-2)&3).  In flight 1 / 2 chunks.
      kvEarly = kvEarlyNext;
      if (j >= 2) {
        u64* sL = MbufK + (((unsigned)(j - 3)) & 3u) * 64;
        kvLate = ld_agent(&sL[lane]);
        u64* sE = MbufK + (((unsigned)(j - 2)) & 3u) * 64;
        kvEarlyNext = ld_agent(&sE[lane]);
      }

      sx = s1x; sy = s1y; s1x = s2x; s1y = s2y;
    }
  } else {
    // ================= scanners: blocks 1..64, one sample each =============
    // iter i (0..123): issue Nb load for chunk i; bulk-scan [0..64i) from LDS
    // (staged in prior iters) under it; wave-0 tail validates the 64 fresh
    // chunk-i nodes, folds one each, publishes tag i+132 into ring slot i&3.
    // M is computed vs chunk (i+4)'s sample -> consumed at merge j=i+4 with
    // tag equality.  Published ~3 chunk periods before use.
    const int b = blk - 1;

    for (int i = 0; i < NCHUNKS - 4; ++i) {
      const int c = i * NCHUNK;

      u64 nv = POISON64;
      if (wave == 0) nv = ld_agent(&Nb[c + lane]);   // issue early, check late

      // my sample: chunk i+4, slot b
      float sx, sy;
      {
        const int ii = (i + 4) * NCHUNK + b;
        const float uu = u[ii];
        if (uu < 0.1f) { sx = gx; sy = gy; }
        else { sx = mul_rn(r[2 * ii], 200.0f); sy = mul_rn(r[2 * ii + 1], 200.0f); }
      }

      // ---- bulk scan of staged nodes [1..64i) + node 0 ----
      u64 key = KEY_MAX;
      if (tid == 0) {
        const float dx = sub_rn(n0x, sx), dy = sub_rn(n0y, sy);
        key = mkkey(add_rn(mul_rn(dx, dx), mul_rn(dy, dy)), 0);
      }
      for (int jj = 1 + 2 * tid; jj < c; jj += 2 * NTHREADS) {
        const float4 p = *(const float4*)&sh.s.nodes[jj - 1];
        const float dxa = sub_rn(p.x, sx), dya = sub_rn(p.y, sy);
        const u64 ka = mkkey(add_rn(mul_rn(dxa, dxa), mul_rn(dya, dya)), jj);
        const float dxb = sub_rn(p.z, sx), dyb = sub_rn(p.w, sy);
        const u64 kb = mkkey(add_rn(mul_rn(dxb, dxb), mul_rn(dyb, dyb)), jj + 1);
        if (ka < key) key = ka;
        if (kb < key) key = kb;
      }
      #pragma unroll
      for (int m = 32; m >= 1; m >>= 1) {
        const u64 ok = __shfl_xor(key, m, 64);
        if (ok < key) key = ok;
      }
      if (lane == 0) sh.s.K[wave] = key;
      __syncthreads();

      // ---- wave-0 tail: validate fresh chunk i, fold, publish, stage ----
      if (wave == 0) {
        u64 kk = (lane < 4) ? sh.s.K[lane] : KEY_MAX;
        u64 ok = __shfl_xor(kk, 1, 64); if (ok < kk) kk = ok;
        ok = __shfl_xor(kk, 2, 64);     if (ok < kk) kk = ok;

        while (!__all((int)(nv != POISON64))) {   // normally already valid
          __builtin_amdgcn_s_sleep(1);
          nv = ld_agent(&Nb[c + lane]);
        }
        compiler_fence();
        const float px = lo32f(nv), py = hi32f(nv);
        {
          const float dx = sub_rn(px, sx), dy = sub_rn(py, sy);
          const u64 ki = mkkey(add_rn(mul_rn(dx, dx), mul_rn(dy, dy)), c + lane + 1);
          if (ki < kk) kk = ki;
        }
        #pragma unroll
        for (int m = 32; m >= 1; m >>= 1) {
          const u64 o2 = __shfl_xor(kk, m, 64);
          if (o2 < kk) kk = o2;
        }
        if (lane == 0) {
          u64* slot = MbufK + (((unsigned)i) & 3u) * 64;
          st_agent(&slot[b], kk | ((u64)(unsigned)(i + 132) << 13));
        }
        float2 p; p.x = px; p.y = py;
        sh.s.nodes[c + lane] = p;         // stage chunk i for next bulk
      }
      // gate: next bulk reads chunk i; K reused next iter.
      __syncthreads();
    }
  }
}

extern "C" void kernel_launch(void* const* d_in, const int* in_sizes, int n_in,
                              void* d_out, int out_size, void* d_ws, size_t ws_size,
                              hipStream_t stream) {
  const float* state = (const float*)d_in[0];
  const float* goal  = (const float*)d_in[1];
  const float* u     = (const float*)d_in[2];
  const float* r     = (const float*)d_in[3];
  float* out = (float*)d_out;
  unsigned* ws = (unsigned*)d_ws;
  (void)in_sizes; (void)n_in; (void)out_size; (void)ws_size;
  rrt_kernel<<<NSCAN + 1, NTHREADS, 0, stream>>>(state, goal, u, r, out, ws);
}